// Round 1
// baseline (199.880 us; speedup 1.0000x reference)
//
#include <hip/hip_runtime.h>
#include <math.h>

// Problem constants (from setup_inputs):
// L=4, B=8, Ns=1200, Nl=128, C=768, H=W=448, STRIDE_S=8, STRIDE_L=28
constexpr int L_  = 4;
constexpr int B_  = 8;
constexpr int NS  = 1200;
constexpr int NL  = 128;
constexpr int C_  = 768;
constexpr int H_  = 448;
constexpr int W_  = 448;
constexpr int NVS = (H_ / 8)  * (W_ / 8);   // 3136
constexpr int NVL = (H_ / 28) * (W_ / 28);  // 256
constexpr int ROWS_S = L_ * B_ * NS;        // 38400
constexpr int ROWS_L = L_ * B_ * NL;        // 4096
constexpr int ROWS   = ROWS_S + ROWS_L;     // 42496

// ---------------------------------------------------------------------------
// K1: valid masks from f_k.  valid_s[b, r*56+c] = f_k[b,0,8r,8c] > 0
//                            valid_l[b, r*16+c] = f_k[b,0,28r,28c] > 0
__global__ __launch_bounds__(256)
void k_valid(const float* __restrict__ f_k,
             unsigned char* __restrict__ valid_s,
             unsigned char* __restrict__ valid_l) {
    int i = blockIdx.x * 256 + threadIdx.x;
    if (i < B_ * NVS) {
        int b = i / NVS, p = i - b * NVS;
        int r = p / 56, c = p - r * 56;
        valid_s[i] = (f_k[b * H_ * W_ + r * 8 * W_ + c * 8] > 0.f) ? 1 : 0;
    } else {
        int j = i - B_ * NVS;
        if (j < B_ * NVL) {
            int b = j / NVL, p = j - b * NVL;
            int r = p / 16, c = p - r * 16;
            valid_l[j] = (f_k[b * H_ * W_ + r * 28 * W_ + c * 28] > 0.f) ? 1 : 0;
        }
    }
}

// ---------------------------------------------------------------------------
// K2: per-row distance + nonzero flag.  One 64-lane wave per (l,b,n) row.
// d[r] = ||kernel[l,b,:] - sel[l,b,n,:]||_2 ; nz[r] = any(sel[l,b,n,:] != 0)
__global__ __launch_bounds__(256)
void k_dist(const float* __restrict__ sel_s, const float* __restrict__ sel_l,
            const float* __restrict__ ker_s, const float* __restrict__ ker_l,
            float* __restrict__ d_s, float* __restrict__ d_l,
            unsigned char* __restrict__ nz_s, unsigned char* __restrict__ nz_l) {
    const int lane = threadIdx.x & 63;
    const int wid  = threadIdx.x >> 6;
    long long row = (long long)blockIdx.x * 4 + wid;
    if (row >= ROWS) return;

    const float* sel; const float* ker; float* dout; unsigned char* nzout;
    long long r; int N;
    if (row < ROWS_S) { r = row;           N = NS; sel = sel_s; ker = ker_s; dout = d_s; nzout = nz_s; }
    else              { r = row - ROWS_S;  N = NL; sel = sel_l; ker = ker_l; dout = d_l; nzout = nz_l; }

    const int lb = (int)(r / N);  // l*B + b
    const float4* __restrict__ srow = (const float4*)(sel + r * (long long)C_);
    const float4* __restrict__ arow = (const float4*)(ker + (long long)lb * C_);

    float acc = 0.f;
    int nz = 0;
#pragma unroll
    for (int j = 0; j < 3; ++j) {            // 192 float4 per row / 64 lanes
        float4 s4 = srow[j * 64 + lane];
        float4 a4 = arow[j * 64 + lane];
        float dx = a4.x - s4.x, dy = a4.y - s4.y;
        float dz = a4.z - s4.z, dw = a4.w - s4.w;
        acc += dx * dx + dy * dy + dz * dz + dw * dw;
        nz |= (s4.x != 0.f) || (s4.y != 0.f) || (s4.z != 0.f) || (s4.w != 0.f);
    }
#pragma unroll
    for (int off = 32; off >= 1; off >>= 1) acc += __shfl_xor(acc, off, 64);
    int wnz = __any(nz);
    if (lane == 0) {
        dout[r]  = sqrtf(acc);
        nzout[r] = (unsigned char)(wnz ? 1 : 0);
    }
}

// ---------------------------------------------------------------------------
// K3: col_valid[l,n] = OR over b of nz[l,b,n]
__global__ __launch_bounds__(256)
void k_colvalid(const unsigned char* __restrict__ nz_s,
                const unsigned char* __restrict__ nz_l,
                unsigned char* __restrict__ cv_s,
                unsigned char* __restrict__ cv_l) {
    int i = blockIdx.x * 256 + threadIdx.x;
    if (i < L_ * NS) {
        int l = i / NS, n = i - l * NS;
        int v = 0;
        for (int b = 0; b < B_; ++b) v |= nz_s[(l * B_ + b) * NS + n];
        cv_s[i] = (unsigned char)v;
    } else {
        int j = i - L_ * NS;
        if (j < L_ * NL) {
            int l = j / NL, n = j - l * NL;
            int v = 0;
            for (int b = 0; b < B_; ++b) v |= nz_l[(l * B_ + b) * NL + n];
            cv_l[j] = (unsigned char)v;
        }
    }
}

// ---------------------------------------------------------------------------
// K4: per-(scale,l,b) masked means -> loss, active.  Blocks 0..31 = scale s,
// 32..63 = scale l.  loss[blk], act[blk].
__global__ __launch_bounds__(256)
void k_stats(const float* __restrict__ d_s, const float* __restrict__ d_l,
             const int* __restrict__ idx_s, const int* __restrict__ idx_l,
             const unsigned char* __restrict__ valid_s,
             const unsigned char* __restrict__ valid_l,
             const unsigned char* __restrict__ cv_s,
             const unsigned char* __restrict__ cv_l,
             float* __restrict__ loss, int* __restrict__ act) {
    const int blk = blockIdx.x;
    const bool large = blk >= 32;
    const int lb = blk & 31;
    const int l = lb / B_, b = lb - l * B_;
    const int N  = large ? NL : NS;
    const int Nv = large ? NVL : NVS;
    const float* d           = large ? d_l : d_s;
    const int* idx           = large ? idx_l : idx_s;
    const unsigned char* val = large ? valid_l : valid_s;
    const unsigned char* cv  = large ? cv_l : cv_s;

    float sp = 0.f, sn = 0.f;
    int cp = 0, cn = 0;
    const long long rowbase = (long long)lb * N;
    for (int n = threadIdx.x; n < N; n += 256) {
        float dv   = d[rowbase + n];
        int member = val[b * Nv + idx[rowbase + n]];
        int colv   = cv[l * N + n];
        int pos = member & colv;
        int neg = (member ^ 1) & colv;
        sp += pos ? dv : 0.f;
        sn += neg ? dv : 0.f;
        cp += pos;
        cn += neg;
    }
#pragma unroll
    for (int off = 32; off >= 1; off >>= 1) {
        sp += __shfl_xor(sp, off, 64);
        sn += __shfl_xor(sn, off, 64);
        cp += __shfl_xor(cp, off, 64);
        cn += __shfl_xor(cn, off, 64);
    }
    __shared__ float ssp[4], ssn[4];
    __shared__ int   scp[4], scn[4];
    const int wid = threadIdx.x >> 6, lane = threadIdx.x & 63;
    if (lane == 0) { ssp[wid] = sp; ssn[wid] = sn; scp[wid] = cp; scn[wid] = cn; }
    __syncthreads();
    if (threadIdx.x == 0) {
        float SP = 0.f, SN = 0.f; int CP = 0, CN = 0;
        for (int w = 0; w < 4; ++w) { SP += ssp[w]; SN += ssn[w]; CP += scp[w]; CN += scn[w]; }
        float ap = SP / (float)(CP > 0 ? CP : 1);
        float an = SN / (float)(CN > 0 ? CN : 1);
        float x  = ap - an;
        // softplus = max(x,0) + log1p(exp(-|x|))
        loss[blk] = fmaxf(x, 0.f) + log1pf(expf(-fabsf(x)));
        act[blk]  = (CP > 0 && CN > 0) ? 1 : 0;
    }
}

// ---------------------------------------------------------------------------
// K5: final scalar.  act_l &= act_s; total / times.
__global__ __launch_bounds__(64)
void k_final(const float* __restrict__ loss, const int* __restrict__ act,
             float* __restrict__ out) {
    int i = threadIdx.x;
    float total = 0.f;
    int times = 0;
    if (i < 32) {
        int as = act[i];
        int al = act[32 + i] & as;
        total = (as ? loss[i] : 0.f) + (al ? loss[32 + i] : 0.f);
        times = as + al;
    }
#pragma unroll
    for (int off = 32; off >= 1; off >>= 1) {
        total += __shfl_xor(total, off, 64);
        times += __shfl_xor(times, off, 64);
    }
    if (i == 0) out[0] = (times > 0) ? (total / (float)times) : 0.f;
}

// ---------------------------------------------------------------------------
extern "C" void kernel_launch(void* const* d_in, const int* in_sizes, int n_in,
                              void* d_out, int out_size, void* d_ws, size_t ws_size,
                              hipStream_t stream) {
    const float* sel_s = (const float*)d_in[0];
    const int*   idx_s = (const int*)  d_in[1];
    const float* sel_l = (const float*)d_in[2];
    const int*   idx_l = (const int*)  d_in[3];
    const float* ker_s = (const float*)d_in[4];
    const float* ker_l = (const float*)d_in[5];
    const float* f_k   = (const float*)d_in[6];
    float* out = (float*)d_out;

    // Workspace carve-out (256B-aligned slots, ~250 KB total).
    char* base = (char*)d_ws;
    size_t o = 0;
    auto alloc = [&](size_t sz) -> char* {
        char* p = base + o;
        o += (sz + 255) & ~(size_t)255;
        return p;
    };
    unsigned char* valid_s = (unsigned char*)alloc(B_ * NVS);
    unsigned char* valid_l = (unsigned char*)alloc(B_ * NVL);
    unsigned char* nz_s    = (unsigned char*)alloc(ROWS_S);
    unsigned char* nz_l    = (unsigned char*)alloc(ROWS_L);
    unsigned char* cv_s    = (unsigned char*)alloc(L_ * NS);
    unsigned char* cv_l    = (unsigned char*)alloc(L_ * NL);
    float* d_s  = (float*)alloc(ROWS_S * sizeof(float));
    float* d_l  = (float*)alloc(ROWS_L * sizeof(float));
    float* loss = (float*)alloc(64 * sizeof(float));
    int*   act  = (int*)alloc(64 * sizeof(int));

    k_valid<<<(B_ * NVS + B_ * NVL + 255) / 256, 256, 0, stream>>>(f_k, valid_s, valid_l);
    k_dist<<<ROWS / 4, 256, 0, stream>>>(sel_s, sel_l, ker_s, ker_l, d_s, d_l, nz_s, nz_l);
    k_colvalid<<<(L_ * NS + L_ * NL + 255) / 256, 256, 0, stream>>>(nz_s, nz_l, cv_s, cv_l);
    k_stats<<<64, 256, 0, stream>>>(d_s, d_l, idx_s, idx_l, valid_s, valid_l, cv_s, cv_l, loss, act);
    k_final<<<1, 64, 0, stream>>>(loss, act, out);
}